// Round 3
// baseline (731.832 us; speedup 1.0000x reference)
//
#include <hip/hip_runtime.h>

// ---------------------------------------------------------------------------
// MEASUREMENT ROUND: byte-identical round-0 kernel, launched TWICE.
// The second launch overwrites out with the identical result (deterministic),
// so correctness is unchanged. The timed-window delta vs round 0 (646 us)
// IS the kernel's true duration K, which top-5 profiling has censored
// (all five visible dispatches are 330-340 us harness fills every round).
//   K = dur_R3 - 646us.
// H_A: K ~ 90  -> dur ~ 735-770 -> kernel at roofline, declare next round.
// H_B: K ~ 300 -> dur ~ 930-970 -> kernel at 1.7 TB/s, input-buffer theory up.
// ---------------------------------------------------------------------------

#define BLOCK 256
#define GPB 4  // graphs per block (= waves per block)

typedef float f4 __attribute__((ext_vector_type(4)));

__global__ __launch_bounds__(BLOCK) void seg_mean_fused(
    const float* __restrict__ feats,
    const int* __restrict__ n_nodes,
    float* __restrict__ out) {
  __shared__ int red[BLOCK];
  __shared__ int offs[GPB];

  const int t = threadIdx.x;
  const int g0 = blockIdx.x * GPB;

  // ---- base = sum(n_nodes[0..g0)), coalesced strided read + tree reduce ----
  int s = 0;
  for (int i = t; i < g0; i += BLOCK) s += n_nodes[i];
  red[t] = s;
  __syncthreads();
#pragma unroll
  for (int d = BLOCK / 2; d > 0; d >>= 1) {
    if (t < d) red[t] += red[t + d];
    __syncthreads();
  }
  if (t == 0) {
    int o = red[0];
#pragma unroll
    for (int j = 0; j < GPB; ++j) {
      offs[j] = o;
      o += n_nodes[g0 + j];
    }
  }
  __syncthreads();

  // ---- one wave per graph: dense column-parallel reduction ----
  const int wave = t >> 6;
  const int lane = t & 63;
  const int g = g0 + wave;
  const int n = n_nodes[g];
  const int start = offs[wave];

  const f4* __restrict__ src =
      reinterpret_cast<const f4*>(feats) + (size_t)start * 64 + lane;

  f4 acc[8];
#pragma unroll
  for (int i = 0; i < 8; ++i) acc[i] = (f4)0.0f;

  int r = 0;
  for (; r + 8 <= n; r += 8) {
#pragma unroll
    for (int i = 0; i < 8; ++i) {
      acc[i] += __builtin_nontemporal_load(&src[(size_t)(r + i) * 64]);
    }
  }
  for (; r < n; ++r) acc[0] += __builtin_nontemporal_load(&src[(size_t)r * 64]);

  f4 total = ((acc[0] + acc[1]) + (acc[2] + acc[3])) +
             ((acc[4] + acc[5]) + (acc[6] + acc[7]));
  total *= (1.0f / (float)n);

  __builtin_nontemporal_store(
      total, &reinterpret_cast<f4*>(out)[(size_t)g * 64 + lane]);
}

extern "C" void kernel_launch(void* const* d_in, const int* in_sizes, int n_in,
                              void* d_out, int out_size, void* d_ws, size_t ws_size,
                              hipStream_t stream) {
  const float* node_feats = (const float*)d_in[0];
  const int* n_nodes = (const int*)d_in[1];
  float* out = (float*)d_out;

  const int b = in_sizes[1];  // 4096 graphs

  // Launch TWICE: second run recomputes the identical output. The duration
  // delta vs the single-launch round-0 bench measures the kernel itself.
  seg_mean_fused<<<b / GPB, BLOCK, 0, stream>>>(node_feats, n_nodes, out);
  seg_mean_fused<<<b / GPB, BLOCK, 0, stream>>>(node_feats, n_nodes, out);
}

// Round 5
// 642.058 us; speedup vs baseline: 1.1398x; 1.1398x over previous
//
#include <hip/hip_runtime.h>

// ---------------------------------------------------------------------------
// Segment-mean over contiguous segments (single fused kernel) — FINAL.
//   in[0]: node_feats  (N_TOTAL=524288, D=256) float32   -- 512 MB, read once
//   in[1]: n_nodes     (B=4096) int32, sums to N_TOTAL
//   out  : graph_feats (B, D) float32                    -- 4 MB
//
// One wave per graph; lane i owns columns [4i,4i+4) as a float4 accumulator.
// Each block of 4 waves computes its base offset by summing the n_nodes
// prefix (16 KB, L2-resident). Feature stream uses nontemporal LOADS
// (read-once; A/B vs plain loads cost +40 us, R0<->R1). Output uses PLAIN
// stores: R4's post-timing check caught a stale-readback flake (absmax
// ~0.089 = exactly one output-sigma -> unwritten-looking lines) attributable
// to nt-store visibility under graph replay; plain stores close it at ~zero
// BW cost (4 MB write either way).
//
// MEASURED AT ROOFLINE (R3 double-launch probe): kernel duration
// K = 731.8 - 646.1 = 85.7 us vs 540.7 MB / 6.3 TB/s = 85.8 us ideal
// -> ~100% of achievable HBM BW. Remaining ~560 us of the timed window is
// harness reset work (2 GiB poison fill ~335 us + small dispatches).
// ---------------------------------------------------------------------------

#define BLOCK 256
#define GPB 4  // graphs per block (= waves per block)

typedef float f4 __attribute__((ext_vector_type(4)));

__global__ __launch_bounds__(BLOCK) void seg_mean_fused(
    const float* __restrict__ feats,
    const int* __restrict__ n_nodes,
    float* __restrict__ out) {
  __shared__ int red[BLOCK];
  __shared__ int offs[GPB];

  const int t = threadIdx.x;
  const int g0 = blockIdx.x * GPB;

  // ---- base = sum(n_nodes[0..g0)), coalesced strided read + tree reduce ----
  int s = 0;
  for (int i = t; i < g0; i += BLOCK) s += n_nodes[i];
  red[t] = s;
  __syncthreads();
#pragma unroll
  for (int d = BLOCK / 2; d > 0; d >>= 1) {
    if (t < d) red[t] += red[t + d];
    __syncthreads();
  }
  if (t == 0) {
    int o = red[0];
#pragma unroll
    for (int j = 0; j < GPB; ++j) {
      offs[j] = o;
      o += n_nodes[g0 + j];
    }
  }
  __syncthreads();

  // ---- one wave per graph: dense column-parallel reduction ----
  const int wave = t >> 6;
  const int lane = t & 63;
  const int g = g0 + wave;
  const int n = n_nodes[g];
  const int start = offs[wave];

  // Row-major f4 view: row r of this graph begins at f4 index (start+r)*64.
  const f4* __restrict__ src =
      reinterpret_cast<const f4*>(feats) + (size_t)start * 64 + lane;

  f4 acc[8];
#pragma unroll
  for (int i = 0; i < 8; ++i) acc[i] = (f4)0.0f;

  int r = 0;
  for (; r + 8 <= n; r += 8) {
#pragma unroll
    for (int i = 0; i < 8; ++i) {
      // read-once stream: nontemporal load (1 KiB per wave per instr)
      acc[i] += __builtin_nontemporal_load(&src[(size_t)(r + i) * 64]);
    }
  }
  for (; r < n; ++r) acc[0] += __builtin_nontemporal_load(&src[(size_t)r * 64]);

  f4 total = ((acc[0] + acc[1]) + (acc[2] + acc[3])) +
             ((acc[4] + acc[5]) + (acc[6] + acc[7]));
  total *= (1.0f / (float)n);

  // plain (cached) store — see header comment
  reinterpret_cast<f4*>(out)[(size_t)g * 64 + lane] = total;
}

extern "C" void kernel_launch(void* const* d_in, const int* in_sizes, int n_in,
                              void* d_out, int out_size, void* d_ws, size_t ws_size,
                              hipStream_t stream) {
  const float* node_feats = (const float*)d_in[0];
  const int* n_nodes = (const int*)d_in[1];
  float* out = (float*)d_out;

  const int b = in_sizes[1];  // 4096 graphs

  seg_mean_fused<<<b / GPB, BLOCK, 0, stream>>>(node_feats, n_nodes, out);
}